// Round 1
// 842.682 us; speedup vs baseline: 1.0392x; 1.0392x over previous
//
#include <hip/hip_runtime.h>

// TGSR: y_t = y_{t-1} + M (x_t - y_{t-1}),  M = inv(L+I) = inv(B).
// R4: all plain kernel launches (kernel boundary = device-wide sync+coherence).
//  - Newton inverse: 2 launches/iter, Sherman-Morrison rank-1 start, 5 iters.
//  - G-powers: G=I-M, 4 hi/lo-split squarings -> G^16 (for chunk carries).
//  - Chunked scan, C=8 chunks of 16 steps: phase1 (local scans -> end states),
//    7 carry GEMMs (Y_c = E_c + G16 Y_{c-1}), phase2 (re-scan with carry-in).
// R5 (this round): XCD-sibling swizzle in phase1/phase2 -- the 4 cg-siblings
//    of a (ch,jt) tile each own a 64B half... quarter of the 256B xs row, so a
//    128B cache line spans cg pairs. Encode bx = cg*64 + ch*8 + jt so siblings
//    share bx mod 8 (same XCD under round-robin dispatch) and their lines are
//    fetched/dirtied once per L2 instead of 2x across XCDs. Plus nontemporal
//    out stores to suppress write-allocate fetches (out is never re-read).

#define NITER 5
#define NPRE  3

typedef _Float16 f16x8 __attribute__((ext_vector_type(8)));
typedef _Float16 f16x4 __attribute__((ext_vector_type(4)));
typedef float    f32x4 __attribute__((ext_vector_type(4)));

#define LDSROW 520
#define ZROW   520

// ---- workspace offsets (bytes) ----
#define OFF_W      0u          // 512 f32
#define OFF_BHI    8192u       // f16 hi(B) row-major        512 KB
#define OFF_BLO    532480u     // f16 lo(B) row-major        512 KB
#define OFF_XF     1056768u    // fp32 X, col-major          1 MB
#define OFF_XRM0   2105344u    // f16(256X) row-major ping   512 KB
#define OFF_XRM1   2629632u    // pong (NITER odd -> final M here)
#define OFF_XHCM   3153920u    // f16 hi(256X) col-major
#define OFF_XLCM   3678208u    // f16 lo(256X) col-major
#define OFF_ECM    4202496u    // f16(32E) col-major
#define OFF_G0     4726784u    // G buf0: [rm_h, rm_l, cm_h, cm_l] x 512 KB = 2 MB
#define OFF_G1     6823936u    // G buf1: same layout
#define OFF_STATE  8921088u    // f16 carry states [c][jt][f][row] = 4 MB
// total ~12.6 MB

#define GSUB 262144  // elements per G sub-array

__device__ __forceinline__ f32x4 MF(f16x8 a, f16x8 b, f32x4 c) {
    return __builtin_amdgcn_mfma_f32_16x16x32_f16(a, b, c, 0, 0, 0);
}
__device__ __forceinline__ unsigned long long pack4(f16x4 v) {
    union { f16x4 v; unsigned long long u; } t; t.v = v; return t.u;
}

// ---------------------------------------------------------------------------
// K1a: rowsums -> w; build B = (D+1)I - A as f16 hi/lo row-major.
// 32 blocks x 256 threads, block owns rows R..R+15.
// ---------------------------------------------------------------------------
__launch_bounds__(256)
__global__ void k_prep_rows(const float* __restrict__ A, unsigned char* __restrict__ wsb)
{
    float* w = (float*)(wsb + OFF_W);
    _Float16* Bhi = (_Float16*)(wsb + OFF_BHI);
    _Float16* Blo = (_Float16*)(wsb + OFF_BLO);
    const int tid = threadIdx.x;
    const int R = blockIdx.x * 16;
    __shared__ float drs[16];
    {
        int row16 = tid >> 4, seg = tid & 15;
        const float4* ap = (const float4*)&A[(size_t)(R + row16) * 512 + seg * 32];
        float p = 0.f;
        #pragma unroll
        for (int j = 0; j < 8; ++j) { float4 v = ap[j]; p += v.x + v.y + v.z + v.w; }
        #pragma unroll
        for (int off = 1; off <= 8; off <<= 1) p += __shfl_xor(p, off, 64);
        if (seg == 0) drs[row16] = p;
    }
    __syncthreads();
    if (tid < 16) w[R + tid] = 1.f / (1.f + drs[tid]);
    for (int idx = tid; idx < 8192; idx += 256) {
        int row = idx >> 9, cc = idx & 511;
        float val = ((cc == R + row) ? (drs[row] + 1.f) : 0.f) - A[(size_t)(R + row) * 512 + cc];
        _Float16 hi = (_Float16)val;
        Bhi[(size_t)(R + row) * 512 + cc] = hi;
        Blo[(size_t)(R + row) * 512 + cc] = (_Float16)(val - (float)hi);
    }
}

// ---------------------------------------------------------------------------
// K1b: X0 = W + (1-w) w^T / s  (Sherman-Morrison start; deflates B's 1-mode).
// 32 blocks x 256 threads, block owns cols C..C+15.
// ---------------------------------------------------------------------------
__launch_bounds__(256)
__global__ void k_init_x(unsigned char* __restrict__ wsb)
{
    const float* w = (const float*)(wsb + OFF_W);
    float*    Xf  = (float*)(wsb + OFF_XF);
    _Float16* Xh  = (_Float16*)(wsb + OFF_XHCM);
    _Float16* Xl  = (_Float16*)(wsb + OFF_XLCM);
    _Float16* Xrm = (_Float16*)(wsb + OFF_XRM0);
    const int tid = threadIdx.x;
    const int C = blockIdx.x * 16;
    __shared__ float wl[512];
    __shared__ float red[4];
    wl[tid] = w[tid]; wl[tid + 256] = w[tid + 256];
    __syncthreads();
    float p = wl[tid] + wl[tid + 256];
    #pragma unroll
    for (int off = 32; off >= 1; off >>= 1) p += __shfl_xor(p, off, 64);
    if ((tid & 63) == 0) red[tid >> 6] = p;
    __syncthreads();
    const float s = red[0] + red[1] + red[2] + red[3];
    for (int idx = tid; idx < 8192; idx += 256) {
        int col = C + (idx >> 9), row = idx & 511;
        float wr = wl[row];
        float xv = ((row == col) ? wr : 0.f) + (1.f - wr) * wl[col] / s;
        Xf[(size_t)col * 512 + row] = xv;
        float sc = xv * 256.f;
        _Float16 h = (_Float16)sc;
        Xh[(size_t)col * 512 + row] = h;
        Xl[(size_t)col * 512 + row] = (_Float16)(sc - (float)h);
        Xrm[(size_t)row * 512 + col] = h;
    }
}

// ---------------------------------------------------------------------------
// K2: E = I - B@X   (acc = 256*(B@X); split 3-product for nit >= NPRE)
// 256 blocks x 256 threads: block (P=bx>>3 -> rows P*16.., jt=bx&7 -> cols jt*64..)
// ---------------------------------------------------------------------------
__launch_bounds__(256)
__global__ void k_newton_e(unsigned char* __restrict__ wsb, int nit)
{
    const _Float16* Bhi = (const _Float16*)(wsb + OFF_BHI);
    const _Float16* Blo = (const _Float16*)(wsb + OFF_BLO);
    const _Float16* Xh  = (const _Float16*)(wsb + OFF_XHCM);
    const _Float16* Xl  = (const _Float16*)(wsb + OFF_XLCM);
    _Float16* Ecm = (_Float16*)(wsb + OFF_ECM);

    const int tid = threadIdx.x;
    const int lane = tid & 63, w = tid >> 6, q = lane >> 4, nI = lane & 15;
    const int bx = blockIdx.x;
    const int jt = bx & 7, R = (bx >> 3) * 16;
    const int c = jt * 64 + w * 16 + nI;

    __shared__ _Float16 pan[2][16 * LDSROW];
    #pragma unroll
    for (int rep = 0; rep < 4; ++rep) {
        int idx = tid + rep * 256; int row = idx >> 6, seg = idx & 63;
        *(f16x8*)&pan[0][row * LDSROW + seg * 8] = *(const f16x8*)&Bhi[(size_t)(R + row) * 512 + seg * 8];
        *(f16x8*)&pan[1][row * LDSROW + seg * 8] = *(const f16x8*)&Blo[(size_t)(R + row) * 512 + seg * 8];
    }
    __syncthreads();

    const _Float16* xh = Xh + (size_t)c * 512;
    const _Float16* xl = Xl + (size_t)c * 512;
    f32x4 acc = {0.f, 0.f, 0.f, 0.f};
    #pragma unroll
    for (int kk = 0; kk < 16; ++kk)
        acc = MF(*(f16x8*)&pan[0][nI * LDSROW + kk * 32 + q * 8], *(const f16x8*)&xh[kk * 32 + q * 8], acc);
    if (nit >= NPRE) {
        #pragma unroll
        for (int kk = 0; kk < 16; ++kk)
            acc = MF(*(f16x8*)&pan[0][nI * LDSROW + kk * 32 + q * 8], *(const f16x8*)&xl[kk * 32 + q * 8], acc);
        #pragma unroll
        for (int kk = 0; kk < 16; ++kk)
            acc = MF(*(f16x8*)&pan[1][nI * LDSROW + kk * 32 + q * 8], *(const f16x8*)&xh[kk * 32 + q * 8], acc);
    }
    f16x4 ev;
    #pragma unroll
    for (int r4 = 0; r4 < 4; ++r4) {
        int row = R + q * 4 + r4;
        float e = ((row == c) ? 1.f : 0.f) - acc[r4] * (1.f / 256.f);
        ev[r4] = (_Float16)(e * 32.f);
    }
    *(f16x4*)&Ecm[(size_t)c * 512 + R + q * 4] = ev;
}

// ---------------------------------------------------------------------------
// K3: X += X@E   (acc = (256X)@(32E) = 8192*(X@E)); fp32 master in Xf (cm).
// ---------------------------------------------------------------------------
__launch_bounds__(256)
__global__ void k_newton_u(unsigned char* __restrict__ wsb, int nit)
{
    const _Float16* Xrm_cur = (const _Float16*)(wsb + ((nit & 1) ? OFF_XRM1 : OFF_XRM0));
    _Float16*       Xrm_nxt = (_Float16*)(wsb + ((nit & 1) ? OFF_XRM0 : OFF_XRM1));
    const _Float16* Ecm = (const _Float16*)(wsb + OFF_ECM);
    float*    Xf = (float*)(wsb + OFF_XF);
    _Float16* Xh = (_Float16*)(wsb + OFF_XHCM);
    _Float16* Xl = (_Float16*)(wsb + OFF_XLCM);

    const int tid = threadIdx.x;
    const int lane = tid & 63, w = tid >> 6, q = lane >> 4, nI = lane & 15;
    const int bx = blockIdx.x;
    const int jt = bx & 7, R = (bx >> 3) * 16;
    const int c = jt * 64 + w * 16 + nI;

    __shared__ _Float16 pan[16 * LDSROW];
    #pragma unroll
    for (int rep = 0; rep < 4; ++rep) {
        int idx = tid + rep * 256; int row = idx >> 6, seg = idx & 63;
        *(f16x8*)&pan[row * LDSROW + seg * 8] = *(const f16x8*)&Xrm_cur[(size_t)(R + row) * 512 + seg * 8];
    }
    __syncthreads();

    const _Float16* ec = Ecm + (size_t)c * 512;
    f32x4 acc = {0.f, 0.f, 0.f, 0.f};
    #pragma unroll
    for (int kk = 0; kk < 16; ++kk)
        acc = MF(*(f16x8*)&pan[nI * LDSROW + kk * 32 + q * 8], *(const f16x8*)&ec[kk * 32 + q * 8], acc);

    f32x4 xv4 = *(f32x4*)&Xf[(size_t)c * 512 + R + q * 4];
    f16x4 h4, l4;
    #pragma unroll
    for (int r4 = 0; r4 < 4; ++r4) {
        float xv = xv4[r4] + acc[r4] * (1.f / 8192.f);
        xv4[r4] = xv;
        float sc = xv * 256.f;
        h4[r4] = (_Float16)sc;
        l4[r4] = (_Float16)(sc - (float)h4[r4]);
    }
    *(f32x4*)&Xf[(size_t)c * 512 + R + q * 4] = xv4;
    *(unsigned long long*)&Xh[(size_t)c * 512 + R + q * 4] = pack4(h4);
    *(unsigned long long*)&Xl[(size_t)c * 512 + R + q * 4] = pack4(l4);
    #pragma unroll
    for (int r4 = 0; r4 < 4; ++r4) {
        int row = R + q * 4 + r4;
        union { _Float16 h; unsigned short s; } cv; cv.h = h4[r4];
        unsigned x = cv.s;
        unsigned px = (unsigned)__shfl_xor((int)x, 1, 64);
        if ((nI & 1) == 0)
            *(unsigned*)&Xrm_nxt[(size_t)row * 512 + c] = x | (px << 16);
    }
}

// ---------------------------------------------------------------------------
// K4: G = I - M  ->  G buf0 as 256*G, hi/lo, row-major + col-major.
// 32 blocks x 256 threads, block owns cols C..C+15.
// ---------------------------------------------------------------------------
__launch_bounds__(256)
__global__ void k_gprep(unsigned char* __restrict__ wsb)
{
    const float* Xf = (const float*)(wsb + OFF_XF);
    _Float16* G = (_Float16*)(wsb + OFF_G0);
    _Float16* Grmh = G, *Grml = G + GSUB, *Gcmh = G + 2 * GSUB, *Gcml = G + 3 * GSUB;
    const int tid = threadIdx.x;
    const int C = blockIdx.x * 16;
    for (int idx = tid; idx < 8192; idx += 256) {
        int col = C + (idx >> 9), row = idx & 511;
        float g = ((row == col) ? 1.f : 0.f) - Xf[(size_t)col * 512 + row];
        float sc = g * 256.f;
        _Float16 h = (_Float16)sc;
        _Float16 l = (_Float16)(sc - (float)h);
        Gcmh[(size_t)col * 512 + row] = h;
        Gcml[(size_t)col * 512 + row] = l;
        Grmh[(size_t)row * 512 + col] = h;
        Grml[(size_t)row * 512 + col] = l;
    }
}

// ---------------------------------------------------------------------------
// K5: G2 = G@G (hi/lo split, 3 products). In: 256*G, out: 256*G^2 (same layout).
// ---------------------------------------------------------------------------
__launch_bounds__(256)
__global__ void k_gsq(const _Float16* __restrict__ Gin, _Float16* __restrict__ Gout)
{
    const _Float16* rmh = Gin, *rml = Gin + GSUB, *cmh = Gin + 2 * GSUB, *cml = Gin + 3 * GSUB;
    _Float16* ormh = Gout; _Float16* orml = Gout + GSUB;
    _Float16* ocmh = Gout + 2 * GSUB; _Float16* ocml = Gout + 3 * GSUB;

    const int tid = threadIdx.x;
    const int lane = tid & 63, w = tid >> 6, q = lane >> 4, nI = lane & 15;
    const int bx = blockIdx.x;
    const int jt = bx & 7, R = (bx >> 3) * 16;
    const int c = jt * 64 + w * 16 + nI;

    __shared__ _Float16 pan[2][16 * LDSROW];
    #pragma unroll
    for (int rep = 0; rep < 4; ++rep) {
        int idx = tid + rep * 256; int row = idx >> 6, seg = idx & 63;
        *(f16x8*)&pan[0][row * LDSROW + seg * 8] = *(const f16x8*)&rmh[(size_t)(R + row) * 512 + seg * 8];
        *(f16x8*)&pan[1][row * LDSROW + seg * 8] = *(const f16x8*)&rml[(size_t)(R + row) * 512 + seg * 8];
    }
    __syncthreads();

    const _Float16* bh = cmh + (size_t)c * 512;
    const _Float16* bl = cml + (size_t)c * 512;
    f32x4 acc = {0.f, 0.f, 0.f, 0.f};
    #pragma unroll
    for (int kk = 0; kk < 16; ++kk) {
        f16x8 ah = *(f16x8*)&pan[0][nI * LDSROW + kk * 32 + q * 8];
        f16x8 al = *(f16x8*)&pan[1][nI * LDSROW + kk * 32 + q * 8];
        f16x8 vh = *(const f16x8*)&bh[kk * 32 + q * 8];
        f16x8 vl = *(const f16x8*)&bl[kk * 32 + q * 8];
        acc = MF(ah, vh, acc);
        acc = MF(ah, vl, acc);
        acc = MF(al, vh, acc);
    }
    f16x4 h4, l4;
    #pragma unroll
    for (int r4 = 0; r4 < 4; ++r4) {
        float v = acc[r4] * (1.f / 256.f);   // 256*G^2
        h4[r4] = (_Float16)v;
        l4[r4] = (_Float16)(v - (float)h4[r4]);
    }
    *(unsigned long long*)&ocmh[(size_t)c * 512 + R + q * 4] = pack4(h4);
    *(unsigned long long*)&ocml[(size_t)c * 512 + R + q * 4] = pack4(l4);
    #pragma unroll
    for (int r4 = 0; r4 < 4; ++r4) {
        int row = R + q * 4 + r4;
        union { _Float16 h; unsigned short s; } cv, cl; cv.h = h4[r4]; cl.h = l4[r4];
        unsigned xh = cv.s, xl = cl.s;
        unsigned pxh = (unsigned)__shfl_xor((int)xh, 1, 64);
        unsigned pxl = (unsigned)__shfl_xor((int)xl, 1, 64);
        if ((nI & 1) == 0) {
            *(unsigned*)&ormh[(size_t)row * 512 + c] = xh | (pxh << 16);
            *(unsigned*)&orml[(size_t)row * 512 + c] = xl | (pxl << 16);
        }
    }
}

// ---------------------------------------------------------------------------
// K6: phase-1 local chunk scan (16 steps, zero init), emit end state (f16 cm).
// 256 blocks x 512 threads.
// XCD swizzle: bx = cg*64 + ch*8 + jt  ->  the 4 cg-siblings of a (ch,jt)
// tile all have bx % 8 == jt, landing on one XCD (round-robin dispatch), so
// the 128B xs lines they split 4 ways are fetched once into a shared L2.
// ---------------------------------------------------------------------------
__launch_bounds__(512, 2)
__global__ void k_phase1(const float* __restrict__ xs, unsigned char* __restrict__ wsb)
{
    const _Float16* Mrm = (const _Float16*)(wsb + OFF_XRM1);   // NITER odd
    _Float16* state = (_Float16*)(wsb + OFF_STATE);

    const int tid = threadIdx.x;
    const int lane = tid & 63, wv = tid >> 6, q = lane >> 4, nI = lane & 15;
    const int bx = blockIdx.x;
    const int cg = bx >> 6, ch = (bx >> 3) & 7, jt = bx & 7;   // XCD-sibling swizzle
    const int rowbase = wv * 64;
    const int f = cg * 16 + nI;

    __shared__ _Float16 Z[2][16 * ZROW];

    f16x8 a0[16], a1[16];
    #pragma unroll
    for (int kk = 0; kk < 16; ++kk)
        a0[kk] = *(const f16x8*)&Mrm[(size_t)(rowbase + nI) * 512 + kk * 32 + q * 8];
    #pragma unroll
    for (int kk = 0; kk < 16; ++kk)
        a1[kk] = *(const f16x8*)&Mrm[(size_t)(rowbase + 16 + nI) * 512 + kk * 32 + q * 8];
    const _Float16* m2 = &Mrm[(size_t)(rowbase + 32 + nI) * 512];
    const _Float16* m3 = &Mrm[(size_t)(rowbase + 48 + nI) * 512];

    f32x4 Y[4] = {{0,0,0,0},{0,0,0,0},{0,0,0,0},{0,0,0,0}};
    float xn[4][4];
    const int tg0 = ch * 16;

    {
        const size_t b0 = ((size_t)(jt * 128 + tg0) * 512) * 64 + f;
        #pragma unroll
        for (int T = 0; T < 4; ++T) {
            f16x4 zv;
            #pragma unroll
            for (int r4 = 0; r4 < 4; ++r4)
                zv[r4] = (_Float16)xs[b0 + (size_t)(rowbase + T * 16 + q * 4 + r4) * 64];
            *(f16x4*)&Z[0][nI * ZROW + rowbase + T * 16 + q * 4] = zv;
        }
        const size_t b1 = ((size_t)(jt * 128 + tg0 + 1) * 512) * 64 + f;
        #pragma unroll
        for (int T = 0; T < 4; ++T)
            #pragma unroll
            for (int r4 = 0; r4 < 4; ++r4)
                xn[T][r4] = xs[b1 + (size_t)(rowbase + T * 16 + q * 4 + r4) * 64];
    }
    __syncthreads();

    for (int t = 0; t < 16; ++t) {
        const _Float16* zb = &Z[t & 1][nI * ZROW];
        f32x4 acc0 = {0,0,0,0}, acc1 = {0,0,0,0}, acc2 = {0,0,0,0}, acc3 = {0,0,0,0};
        #pragma unroll
        for (int kk = 0; kk < 16; ++kk) {
            f16x8 b  = *(const f16x8*)&zb[kk * 32 + q * 8];
            f16x8 v2 = *(const f16x8*)&m2[kk * 32 + q * 8];
            f16x8 v3 = *(const f16x8*)&m3[kk * 32 + q * 8];
            acc0 = MF(a0[kk], b, acc0);
            acc1 = MF(a1[kk], b, acc1);
            acc2 = MF(v2,     b, acc2);
            acc3 = MF(v3,     b, acc3);
        }
        #pragma unroll
        for (int r4 = 0; r4 < 4; ++r4) {
            Y[0][r4] += acc0[r4] * (1.f / 256.f);
            Y[1][r4] += acc1[r4] * (1.f / 256.f);
            Y[2][r4] += acc2[r4] * (1.f / 256.f);
            Y[3][r4] += acc3[r4] * (1.f / 256.f);
        }
        if (t < 15) {
            _Float16* zn = &Z[(t + 1) & 1][nI * ZROW];
            #pragma unroll
            for (int T = 0; T < 4; ++T) {
                f16x4 zv;
                #pragma unroll
                for (int r4 = 0; r4 < 4; ++r4)
                    zv[r4] = (_Float16)(xn[T][r4] - Y[T][r4]);
                *(f16x4*)&zn[rowbase + T * 16 + q * 4] = zv;
            }
            if (t < 14) {
                const size_t bn = ((size_t)(jt * 128 + tg0 + t + 2) * 512) * 64 + f;
                #pragma unroll
                for (int T = 0; T < 4; ++T)
                    #pragma unroll
                    for (int r4 = 0; r4 < 4; ++r4)
                        xn[T][r4] = xs[bn + (size_t)(rowbase + T * 16 + q * 4 + r4) * 64];
            }
            __syncthreads();
        }
    }

    _Float16* st = state + ((size_t)(ch * 8 + jt) * 64 + f) * 512;
    #pragma unroll
    for (int T = 0; T < 4; ++T) {
        f16x4 sv;
        #pragma unroll
        for (int r4 = 0; r4 < 4; ++r4) sv[r4] = (_Float16)Y[T][r4];
        *(unsigned long long*)&st[rowbase + T * 16 + q * 4] = pack4(sv);
    }
}

// ---------------------------------------------------------------------------
// K7: carry update for chunk cch: state[cch] += G16 @ state[cch-1]  (in place).
// 32 blocks x 512 threads: bx = jt*4 + cg.
// ---------------------------------------------------------------------------
__launch_bounds__(512)
__global__ void k_carry(unsigned char* __restrict__ wsb, int cch)
{
    const _Float16* G16h = (const _Float16*)(wsb + OFF_G0);           // rm hi (256*G16)
    const _Float16* G16l = (const _Float16*)(wsb + OFF_G0) + GSUB;    // rm lo
    _Float16* state = (_Float16*)(wsb + OFF_STATE);

    const int tid = threadIdx.x;
    const int lane = tid & 63, wv = tid >> 6, q = lane >> 4, nI = lane & 15;
    const int bx = blockIdx.x;
    const int jt = bx >> 2, cg = bx & 3;
    const int rowbase = wv * 64;
    const int f = cg * 16 + nI;

    const _Float16* yprev = state + ((size_t)((cch - 1) * 8 + jt) * 64 + f) * 512;
    _Float16*       ycur  = state + ((size_t)(cch * 8 + jt) * 64 + f) * 512;

    f32x4 acc[4] = {{0,0,0,0},{0,0,0,0},{0,0,0,0},{0,0,0,0}};
    #pragma unroll 4
    for (int kk = 0; kk < 16; ++kk) {
        f16x8 b = *(const f16x8*)&yprev[kk * 32 + q * 8];
        #pragma unroll
        for (int T = 0; T < 4; ++T) {
            f16x8 ah = *(const f16x8*)&G16h[(size_t)(rowbase + T * 16 + nI) * 512 + kk * 32 + q * 8];
            f16x8 al = *(const f16x8*)&G16l[(size_t)(rowbase + T * 16 + nI) * 512 + kk * 32 + q * 8];
            acc[T] = MF(ah, b, acc[T]);
            acc[T] = MF(al, b, acc[T]);
        }
    }
    #pragma unroll
    for (int T = 0; T < 4; ++T) {
        f16x4 e4 = *(f16x4*)&ycur[rowbase + T * 16 + q * 4];
        f16x4 nv;
        #pragma unroll
        for (int r4 = 0; r4 < 4; ++r4)
            nv[r4] = (_Float16)((float)e4[r4] + acc[T][r4] * (1.f / 256.f));
        *(unsigned long long*)&ycur[rowbase + T * 16 + q * 4] = pack4(nv);
    }
}

// ---------------------------------------------------------------------------
// K8: phase-2 final chunk scan with carry-in; writes out.
// Same XCD-sibling swizzle as K6; out stores are nontemporal (never re-read,
// suppress L2 write-allocate fetch of the out lines).
// ---------------------------------------------------------------------------
__launch_bounds__(512, 2)
__global__ void k_phase2(const float* __restrict__ xs, unsigned char* __restrict__ wsb,
                         float* __restrict__ out)
{
    const _Float16* Mrm = (const _Float16*)(wsb + OFF_XRM1);
    const _Float16* state = (const _Float16*)(wsb + OFF_STATE);

    const int tid = threadIdx.x;
    const int lane = tid & 63, wv = tid >> 6, q = lane >> 4, nI = lane & 15;
    const int bx = blockIdx.x;
    const int cg = bx >> 6, ch = (bx >> 3) & 7, jt = bx & 7;   // XCD-sibling swizzle
    const int rowbase = wv * 64;
    const int f = cg * 16 + nI;

    __shared__ _Float16 Z[2][16 * ZROW];

    f16x8 a0[16], a1[16];
    #pragma unroll
    for (int kk = 0; kk < 16; ++kk)
        a0[kk] = *(const f16x8*)&Mrm[(size_t)(rowbase + nI) * 512 + kk * 32 + q * 8];
    #pragma unroll
    for (int kk = 0; kk < 16; ++kk)
        a1[kk] = *(const f16x8*)&Mrm[(size_t)(rowbase + 16 + nI) * 512 + kk * 32 + q * 8];
    const _Float16* m2 = &Mrm[(size_t)(rowbase + 32 + nI) * 512];
    const _Float16* m3 = &Mrm[(size_t)(rowbase + 48 + nI) * 512];

    f32x4 Y[4];
    if (ch == 0) {
        #pragma unroll
        for (int T = 0; T < 4; ++T)
            #pragma unroll
            for (int r4 = 0; r4 < 4; ++r4) Y[T][r4] = 0.f;
    } else {
        const _Float16* st = state + ((size_t)((ch - 1) * 8 + jt) * 64 + f) * 512;
        #pragma unroll
        for (int T = 0; T < 4; ++T) {
            f16x4 sv = *(const f16x4*)&st[rowbase + T * 16 + q * 4];
            #pragma unroll
            for (int r4 = 0; r4 < 4; ++r4) Y[T][r4] = (float)sv[r4];
        }
    }

    float xn[4][4];
    const int tg0 = ch * 16;
    {
        const size_t b0 = ((size_t)(jt * 128 + tg0) * 512) * 64 + f;
        #pragma unroll
        for (int T = 0; T < 4; ++T) {
            f16x4 zv;
            #pragma unroll
            for (int r4 = 0; r4 < 4; ++r4) {
                float xv = xs[b0 + (size_t)(rowbase + T * 16 + q * 4 + r4) * 64];
                zv[r4] = (_Float16)(xv - Y[T][r4]);
            }
            *(f16x4*)&Z[0][nI * ZROW + rowbase + T * 16 + q * 4] = zv;
        }
        const size_t b1 = ((size_t)(jt * 128 + tg0 + 1) * 512) * 64 + f;
        #pragma unroll
        for (int T = 0; T < 4; ++T)
            #pragma unroll
            for (int r4 = 0; r4 < 4; ++r4)
                xn[T][r4] = xs[b1 + (size_t)(rowbase + T * 16 + q * 4 + r4) * 64];
    }
    __syncthreads();

    for (int t = 0; t < 16; ++t) {
        const _Float16* zb = &Z[t & 1][nI * ZROW];
        f32x4 acc0 = {0,0,0,0}, acc1 = {0,0,0,0}, acc2 = {0,0,0,0}, acc3 = {0,0,0,0};
        #pragma unroll
        for (int kk = 0; kk < 16; ++kk) {
            f16x8 b  = *(const f16x8*)&zb[kk * 32 + q * 8];
            f16x8 v2 = *(const f16x8*)&m2[kk * 32 + q * 8];
            f16x8 v3 = *(const f16x8*)&m3[kk * 32 + q * 8];
            acc0 = MF(a0[kk], b, acc0);
            acc1 = MF(a1[kk], b, acc1);
            acc2 = MF(v2,     b, acc2);
            acc3 = MF(v3,     b, acc3);
        }
        const size_t base = ((size_t)(jt * 128 + tg0 + t) * 512) * 64 + f;
        #pragma unroll
        for (int r4 = 0; r4 < 4; ++r4) {
            Y[0][r4] += acc0[r4] * (1.f / 256.f);
            Y[1][r4] += acc1[r4] * (1.f / 256.f);
            Y[2][r4] += acc2[r4] * (1.f / 256.f);
            Y[3][r4] += acc3[r4] * (1.f / 256.f);
        }
        #pragma unroll
        for (int T = 0; T < 4; ++T)
            #pragma unroll
            for (int r4 = 0; r4 < 4; ++r4)
                __builtin_nontemporal_store(Y[T][r4],
                    &out[base + (size_t)(rowbase + T * 16 + q * 4 + r4) * 64]);

        if (t < 15) {
            _Float16* zn = &Z[(t + 1) & 1][nI * ZROW];
            #pragma unroll
            for (int T = 0; T < 4; ++T) {
                f16x4 zv;
                #pragma unroll
                for (int r4 = 0; r4 < 4; ++r4)
                    zv[r4] = (_Float16)(xn[T][r4] - Y[T][r4]);
                *(f16x4*)&zn[rowbase + T * 16 + q * 4] = zv;
            }
            if (t < 14) {
                const size_t bn = ((size_t)(jt * 128 + tg0 + t + 2) * 512) * 64 + f;
                #pragma unroll
                for (int T = 0; T < 4; ++T)
                    #pragma unroll
                    for (int r4 = 0; r4 < 4; ++r4)
                        xn[T][r4] = xs[bn + (size_t)(rowbase + T * 16 + q * 4 + r4) * 64];
            }
            __syncthreads();
        }
    }
}

extern "C" void kernel_launch(void* const* d_in, const int* in_sizes, int n_in,
                              void* d_out, int out_size, void* d_ws, size_t ws_size,
                              hipStream_t stream)
{
    const float* xs = (const float*)d_in[0];   // [8,128,512,64] fp32
    const float* A  = (const float*)d_in[1];   // [1,512,512] fp32
    float* out = (float*)d_out;                // [8,128,512,64] fp32
    unsigned char* ws = (unsigned char*)d_ws;  // ~12.6 MB used

    k_prep_rows<<<dim3(32), dim3(256), 0, stream>>>(A, ws);
    k_init_x<<<dim3(32), dim3(256), 0, stream>>>(ws);

    for (int nit = 0; nit < NITER; ++nit) {
        k_newton_e<<<dim3(256), dim3(256), 0, stream>>>(ws, nit);
        k_newton_u<<<dim3(256), dim3(256), 0, stream>>>(ws, nit);
    }

    k_gprep<<<dim3(32), dim3(256), 0, stream>>>(ws);
    _Float16* G0 = (_Float16*)(ws + OFF_G0);
    _Float16* G1 = (_Float16*)(ws + OFF_G1);
    k_gsq<<<dim3(256), dim3(256), 0, stream>>>(G0, G1);   // G^2
    k_gsq<<<dim3(256), dim3(256), 0, stream>>>(G1, G0);   // G^4
    k_gsq<<<dim3(256), dim3(256), 0, stream>>>(G0, G1);   // G^8
    k_gsq<<<dim3(256), dim3(256), 0, stream>>>(G1, G0);   // G^16 -> buf0

    k_phase1<<<dim3(256), dim3(512), 0, stream>>>(xs, ws);
    for (int c = 1; c < 8; ++c)
        k_carry<<<dim3(32), dim3(512), 0, stream>>>(ws, c);
    k_phase2<<<dim3(256), dim3(512), 0, stream>>>(xs, ws, out);
}

// Round 2
// 838.469 us; speedup vs baseline: 1.0444x; 1.0050x over previous
//
#include <hip/hip_runtime.h>

// TGSR: y_t = y_{t-1} + M (x_t - y_{t-1}),  M = inv(L+I) = inv(B).
// R4: all plain kernel launches (kernel boundary = device-wide sync+coherence).
//  - Newton inverse: 2 launches/iter, Sherman-Morrison rank-1 start, 5 iters.
//  - G-powers: G=I-M, 4 hi/lo-split squarings -> G^16 (for chunk carries).
//  - Chunked scan, C=8 chunks of 16 steps: phase1 (local scans -> end states),
//    7 carry GEMMs (Y_c = E_c + G16 Y_{c-1}), phase2 (re-scan with carry-in).
// R5: XCD-sibling swizzle (bx = cg*64+ch*8+jt) + nontemporal out stores.
//     Result: FETCH -70MB, dur ~flat -> phase2 is NOT BW-bound at 3.3TB/s.
// R6 (this round): __launch_bounds__(512,2) capped VGPRs at 128, but the
//     persistent A-fragments a0[16]+a1[16] alone are 128 VGPRs -> the 16-step
//     loop was spill/reload-thrashing scratch (~235MB unexplained FETCH,
//     28k-cycle steps, all pipes idle). Grid=256 blocks on 256 CUs means the
//     "2 blocks/CU" guarantee bought nothing. Drop to (512,1): 256-VGPR
//     budget, no spills, same occupancy.

#define NITER 5
#define NPRE  3

typedef _Float16 f16x8 __attribute__((ext_vector_type(8)));
typedef _Float16 f16x4 __attribute__((ext_vector_type(4)));
typedef float    f32x4 __attribute__((ext_vector_type(4)));

#define LDSROW 520
#define ZROW   520

// ---- workspace offsets (bytes) ----
#define OFF_W      0u          // 512 f32
#define OFF_BHI    8192u       // f16 hi(B) row-major        512 KB
#define OFF_BLO    532480u     // f16 lo(B) row-major        512 KB
#define OFF_XF     1056768u    // fp32 X, col-major          1 MB
#define OFF_XRM0   2105344u    // f16(256X) row-major ping   512 KB
#define OFF_XRM1   2629632u    // pong (NITER odd -> final M here)
#define OFF_XHCM   3153920u    // f16 hi(256X) col-major
#define OFF_XLCM   3678208u    // f16 lo(256X) col-major
#define OFF_ECM    4202496u    // f16(32E) col-major
#define OFF_G0     4726784u    // G buf0: [rm_h, rm_l, cm_h, cm_l] x 512 KB = 2 MB
#define OFF_G1     6823936u    // G buf1: same layout
#define OFF_STATE  8921088u    // f16 carry states [c][jt][f][row] = 4 MB
// total ~12.6 MB

#define GSUB 262144  // elements per G sub-array

__device__ __forceinline__ f32x4 MF(f16x8 a, f16x8 b, f32x4 c) {
    return __builtin_amdgcn_mfma_f32_16x16x32_f16(a, b, c, 0, 0, 0);
}
__device__ __forceinline__ unsigned long long pack4(f16x4 v) {
    union { f16x4 v; unsigned long long u; } t; t.v = v; return t.u;
}

// ---------------------------------------------------------------------------
// K1a: rowsums -> w; build B = (D+1)I - A as f16 hi/lo row-major.
// 32 blocks x 256 threads, block owns rows R..R+15.
// ---------------------------------------------------------------------------
__launch_bounds__(256)
__global__ void k_prep_rows(const float* __restrict__ A, unsigned char* __restrict__ wsb)
{
    float* w = (float*)(wsb + OFF_W);
    _Float16* Bhi = (_Float16*)(wsb + OFF_BHI);
    _Float16* Blo = (_Float16*)(wsb + OFF_BLO);
    const int tid = threadIdx.x;
    const int R = blockIdx.x * 16;
    __shared__ float drs[16];
    {
        int row16 = tid >> 4, seg = tid & 15;
        const float4* ap = (const float4*)&A[(size_t)(R + row16) * 512 + seg * 32];
        float p = 0.f;
        #pragma unroll
        for (int j = 0; j < 8; ++j) { float4 v = ap[j]; p += v.x + v.y + v.z + v.w; }
        #pragma unroll
        for (int off = 1; off <= 8; off <<= 1) p += __shfl_xor(p, off, 64);
        if (seg == 0) drs[row16] = p;
    }
    __syncthreads();
    if (tid < 16) w[R + tid] = 1.f / (1.f + drs[tid]);
    for (int idx = tid; idx < 8192; idx += 256) {
        int row = idx >> 9, cc = idx & 511;
        float val = ((cc == R + row) ? (drs[row] + 1.f) : 0.f) - A[(size_t)(R + row) * 512 + cc];
        _Float16 hi = (_Float16)val;
        Bhi[(size_t)(R + row) * 512 + cc] = hi;
        Blo[(size_t)(R + row) * 512 + cc] = (_Float16)(val - (float)hi);
    }
}

// ---------------------------------------------------------------------------
// K1b: X0 = W + (1-w) w^T / s  (Sherman-Morrison start; deflates B's 1-mode).
// 32 blocks x 256 threads, block owns cols C..C+15.
// ---------------------------------------------------------------------------
__launch_bounds__(256)
__global__ void k_init_x(unsigned char* __restrict__ wsb)
{
    const float* w = (const float*)(wsb + OFF_W);
    float*    Xf  = (float*)(wsb + OFF_XF);
    _Float16* Xh  = (_Float16*)(wsb + OFF_XHCM);
    _Float16* Xl  = (_Float16*)(wsb + OFF_XLCM);
    _Float16* Xrm = (_Float16*)(wsb + OFF_XRM0);
    const int tid = threadIdx.x;
    const int C = blockIdx.x * 16;
    __shared__ float wl[512];
    __shared__ float red[4];
    wl[tid] = w[tid]; wl[tid + 256] = w[tid + 256];
    __syncthreads();
    float p = wl[tid] + wl[tid + 256];
    #pragma unroll
    for (int off = 32; off >= 1; off >>= 1) p += __shfl_xor(p, off, 64);
    if ((tid & 63) == 0) red[tid >> 6] = p;
    __syncthreads();
    const float s = red[0] + red[1] + red[2] + red[3];
    for (int idx = tid; idx < 8192; idx += 256) {
        int col = C + (idx >> 9), row = idx & 511;
        float wr = wl[row];
        float xv = ((row == col) ? wr : 0.f) + (1.f - wr) * wl[col] / s;
        Xf[(size_t)col * 512 + row] = xv;
        float sc = xv * 256.f;
        _Float16 h = (_Float16)sc;
        Xh[(size_t)col * 512 + row] = h;
        Xl[(size_t)col * 512 + row] = (_Float16)(sc - (float)h);
        Xrm[(size_t)row * 512 + col] = h;
    }
}

// ---------------------------------------------------------------------------
// K2: E = I - B@X   (acc = 256*(B@X); split 3-product for nit >= NPRE)
// 256 blocks x 256 threads: block (P=bx>>3 -> rows P*16.., jt=bx&7 -> cols jt*64..)
// ---------------------------------------------------------------------------
__launch_bounds__(256)
__global__ void k_newton_e(unsigned char* __restrict__ wsb, int nit)
{
    const _Float16* Bhi = (const _Float16*)(wsb + OFF_BHI);
    const _Float16* Blo = (const _Float16*)(wsb + OFF_BLO);
    const _Float16* Xh  = (const _Float16*)(wsb + OFF_XHCM);
    const _Float16* Xl  = (const _Float16*)(wsb + OFF_XLCM);
    _Float16* Ecm = (_Float16*)(wsb + OFF_ECM);

    const int tid = threadIdx.x;
    const int lane = tid & 63, w = tid >> 6, q = lane >> 4, nI = lane & 15;
    const int bx = blockIdx.x;
    const int jt = bx & 7, R = (bx >> 3) * 16;
    const int c = jt * 64 + w * 16 + nI;

    __shared__ _Float16 pan[2][16 * LDSROW];
    #pragma unroll
    for (int rep = 0; rep < 4; ++rep) {
        int idx = tid + rep * 256; int row = idx >> 6, seg = idx & 63;
        *(f16x8*)&pan[0][row * LDSROW + seg * 8] = *(const f16x8*)&Bhi[(size_t)(R + row) * 512 + seg * 8];
        *(f16x8*)&pan[1][row * LDSROW + seg * 8] = *(const f16x8*)&Blo[(size_t)(R + row) * 512 + seg * 8];
    }
    __syncthreads();

    const _Float16* xh = Xh + (size_t)c * 512;
    const _Float16* xl = Xl + (size_t)c * 512;
    f32x4 acc = {0.f, 0.f, 0.f, 0.f};
    #pragma unroll
    for (int kk = 0; kk < 16; ++kk)
        acc = MF(*(f16x8*)&pan[0][nI * LDSROW + kk * 32 + q * 8], *(const f16x8*)&xh[kk * 32 + q * 8], acc);
    if (nit >= NPRE) {
        #pragma unroll
        for (int kk = 0; kk < 16; ++kk)
            acc = MF(*(f16x8*)&pan[0][nI * LDSROW + kk * 32 + q * 8], *(const f16x8*)&xl[kk * 32 + q * 8], acc);
        #pragma unroll
        for (int kk = 0; kk < 16; ++kk)
            acc = MF(*(f16x8*)&pan[1][nI * LDSROW + kk * 32 + q * 8], *(const f16x8*)&xh[kk * 32 + q * 8], acc);
    }
    f16x4 ev;
    #pragma unroll
    for (int r4 = 0; r4 < 4; ++r4) {
        int row = R + q * 4 + r4;
        float e = ((row == c) ? 1.f : 0.f) - acc[r4] * (1.f / 256.f);
        ev[r4] = (_Float16)(e * 32.f);
    }
    *(f16x4*)&Ecm[(size_t)c * 512 + R + q * 4] = ev;
}

// ---------------------------------------------------------------------------
// K3: X += X@E   (acc = (256X)@(32E) = 8192*(X@E)); fp32 master in Xf (cm).
// ---------------------------------------------------------------------------
__launch_bounds__(256)
__global__ void k_newton_u(unsigned char* __restrict__ wsb, int nit)
{
    const _Float16* Xrm_cur = (const _Float16*)(wsb + ((nit & 1) ? OFF_XRM1 : OFF_XRM0));
    _Float16*       Xrm_nxt = (_Float16*)(wsb + ((nit & 1) ? OFF_XRM0 : OFF_XRM1));
    const _Float16* Ecm = (const _Float16*)(wsb + OFF_ECM);
    float*    Xf = (float*)(wsb + OFF_XF);
    _Float16* Xh = (_Float16*)(wsb + OFF_XHCM);
    _Float16* Xl = (_Float16*)(wsb + OFF_XLCM);

    const int tid = threadIdx.x;
    const int lane = tid & 63, w = tid >> 6, q = lane >> 4, nI = lane & 15;
    const int bx = blockIdx.x;
    const int jt = bx & 7, R = (bx >> 3) * 16;
    const int c = jt * 64 + w * 16 + nI;

    __shared__ _Float16 pan[16 * LDSROW];
    #pragma unroll
    for (int rep = 0; rep < 4; ++rep) {
        int idx = tid + rep * 256; int row = idx >> 6, seg = idx & 63;
        *(f16x8*)&pan[row * LDSROW + seg * 8] = *(const f16x8*)&Xrm_cur[(size_t)(R + row) * 512 + seg * 8];
    }
    __syncthreads();

    const _Float16* ec = Ecm + (size_t)c * 512;
    f32x4 acc = {0.f, 0.f, 0.f, 0.f};
    #pragma unroll
    for (int kk = 0; kk < 16; ++kk)
        acc = MF(*(f16x8*)&pan[nI * LDSROW + kk * 32 + q * 8], *(const f16x8*)&ec[kk * 32 + q * 8], acc);

    f32x4 xv4 = *(f32x4*)&Xf[(size_t)c * 512 + R + q * 4];
    f16x4 h4, l4;
    #pragma unroll
    for (int r4 = 0; r4 < 4; ++r4) {
        float xv = xv4[r4] + acc[r4] * (1.f / 8192.f);
        xv4[r4] = xv;
        float sc = xv * 256.f;
        h4[r4] = (_Float16)sc;
        l4[r4] = (_Float16)(sc - (float)h4[r4]);
    }
    *(f32x4*)&Xf[(size_t)c * 512 + R + q * 4] = xv4;
    *(unsigned long long*)&Xh[(size_t)c * 512 + R + q * 4] = pack4(h4);
    *(unsigned long long*)&Xl[(size_t)c * 512 + R + q * 4] = pack4(l4);
    #pragma unroll
    for (int r4 = 0; r4 < 4; ++r4) {
        int row = R + q * 4 + r4;
        union { _Float16 h; unsigned short s; } cv; cv.h = h4[r4];
        unsigned x = cv.s;
        unsigned px = (unsigned)__shfl_xor((int)x, 1, 64);
        if ((nI & 1) == 0)
            *(unsigned*)&Xrm_nxt[(size_t)row * 512 + c] = x | (px << 16);
    }
}

// ---------------------------------------------------------------------------
// K4: G = I - M  ->  G buf0 as 256*G, hi/lo, row-major + col-major.
// 32 blocks x 256 threads, block owns cols C..C+15.
// ---------------------------------------------------------------------------
__launch_bounds__(256)
__global__ void k_gprep(unsigned char* __restrict__ wsb)
{
    const float* Xf = (const float*)(wsb + OFF_XF);
    _Float16* G = (_Float16*)(wsb + OFF_G0);
    _Float16* Grmh = G, *Grml = G + GSUB, *Gcmh = G + 2 * GSUB, *Gcml = G + 3 * GSUB;
    const int tid = threadIdx.x;
    const int C = blockIdx.x * 16;
    for (int idx = tid; idx < 8192; idx += 256) {
        int col = C + (idx >> 9), row = idx & 511;
        float g = ((row == col) ? 1.f : 0.f) - Xf[(size_t)col * 512 + row];
        float sc = g * 256.f;
        _Float16 h = (_Float16)sc;
        _Float16 l = (_Float16)(sc - (float)h);
        Gcmh[(size_t)col * 512 + row] = h;
        Gcml[(size_t)col * 512 + row] = l;
        Grmh[(size_t)row * 512 + col] = h;
        Grml[(size_t)row * 512 + col] = l;
    }
}

// ---------------------------------------------------------------------------
// K5: G2 = G@G (hi/lo split, 3 products). In: 256*G, out: 256*G^2 (same layout).
// ---------------------------------------------------------------------------
__launch_bounds__(256)
__global__ void k_gsq(const _Float16* __restrict__ Gin, _Float16* __restrict__ Gout)
{
    const _Float16* rmh = Gin, *rml = Gin + GSUB, *cmh = Gin + 2 * GSUB, *cml = Gin + 3 * GSUB;
    _Float16* ormh = Gout; _Float16* orml = Gout + GSUB;
    _Float16* ocmh = Gout + 2 * GSUB; _Float16* ocml = Gout + 3 * GSUB;

    const int tid = threadIdx.x;
    const int lane = tid & 63, w = tid >> 6, q = lane >> 4, nI = lane & 15;
    const int bx = blockIdx.x;
    const int jt = bx & 7, R = (bx >> 3) * 16;
    const int c = jt * 64 + w * 16 + nI;

    __shared__ _Float16 pan[2][16 * LDSROW];
    #pragma unroll
    for (int rep = 0; rep < 4; ++rep) {
        int idx = tid + rep * 256; int row = idx >> 6, seg = idx & 63;
        *(f16x8*)&pan[0][row * LDSROW + seg * 8] = *(const f16x8*)&rmh[(size_t)(R + row) * 512 + seg * 8];
        *(f16x8*)&pan[1][row * LDSROW + seg * 8] = *(const f16x8*)&rml[(size_t)(R + row) * 512 + seg * 8];
    }
    __syncthreads();

    const _Float16* bh = cmh + (size_t)c * 512;
    const _Float16* bl = cml + (size_t)c * 512;
    f32x4 acc = {0.f, 0.f, 0.f, 0.f};
    #pragma unroll
    for (int kk = 0; kk < 16; ++kk) {
        f16x8 ah = *(f16x8*)&pan[0][nI * LDSROW + kk * 32 + q * 8];
        f16x8 al = *(f16x8*)&pan[1][nI * LDSROW + kk * 32 + q * 8];
        f16x8 vh = *(const f16x8*)&bh[kk * 32 + q * 8];
        f16x8 vl = *(const f16x8*)&bl[kk * 32 + q * 8];
        acc = MF(ah, vh, acc);
        acc = MF(ah, vl, acc);
        acc = MF(al, vh, acc);
    }
    f16x4 h4, l4;
    #pragma unroll
    for (int r4 = 0; r4 < 4; ++r4) {
        float v = acc[r4] * (1.f / 256.f);   // 256*G^2
        h4[r4] = (_Float16)v;
        l4[r4] = (_Float16)(v - (float)h4[r4]);
    }
    *(unsigned long long*)&ocmh[(size_t)c * 512 + R + q * 4] = pack4(h4);
    *(unsigned long long*)&ocml[(size_t)c * 512 + R + q * 4] = pack4(l4);
    #pragma unroll
    for (int r4 = 0; r4 < 4; ++r4) {
        int row = R + q * 4 + r4;
        union { _Float16 h; unsigned short s; } cv, cl; cv.h = h4[r4]; cl.h = l4[r4];
        unsigned xh = cv.s, xl = cl.s;
        unsigned pxh = (unsigned)__shfl_xor((int)xh, 1, 64);
        unsigned pxl = (unsigned)__shfl_xor((int)xl, 1, 64);
        if ((nI & 1) == 0) {
            *(unsigned*)&ormh[(size_t)row * 512 + c] = xh | (pxh << 16);
            *(unsigned*)&orml[(size_t)row * 512 + c] = xl | (pxl << 16);
        }
    }
}

// ---------------------------------------------------------------------------
// K6: phase-1 local chunk scan (16 steps, zero init), emit end state (f16 cm).
// 256 blocks x 512 threads.
// XCD swizzle: bx = cg*64 + ch*8 + jt. launch_bounds(512,1): 256-VGPR budget
// (a0+a1 fragments alone need 128) -- grid==CU count so occupancy unchanged.
// ---------------------------------------------------------------------------
__launch_bounds__(512, 1)
__global__ void k_phase1(const float* __restrict__ xs, unsigned char* __restrict__ wsb)
{
    const _Float16* Mrm = (const _Float16*)(wsb + OFF_XRM1);   // NITER odd
    _Float16* state = (_Float16*)(wsb + OFF_STATE);

    const int tid = threadIdx.x;
    const int lane = tid & 63, wv = tid >> 6, q = lane >> 4, nI = lane & 15;
    const int bx = blockIdx.x;
    const int cg = bx >> 6, ch = (bx >> 3) & 7, jt = bx & 7;   // XCD-sibling swizzle
    const int rowbase = wv * 64;
    const int f = cg * 16 + nI;

    __shared__ _Float16 Z[2][16 * ZROW];

    f16x8 a0[16], a1[16];
    #pragma unroll
    for (int kk = 0; kk < 16; ++kk)
        a0[kk] = *(const f16x8*)&Mrm[(size_t)(rowbase + nI) * 512 + kk * 32 + q * 8];
    #pragma unroll
    for (int kk = 0; kk < 16; ++kk)
        a1[kk] = *(const f16x8*)&Mrm[(size_t)(rowbase + 16 + nI) * 512 + kk * 32 + q * 8];
    const _Float16* m2 = &Mrm[(size_t)(rowbase + 32 + nI) * 512];
    const _Float16* m3 = &Mrm[(size_t)(rowbase + 48 + nI) * 512];

    f32x4 Y[4] = {{0,0,0,0},{0,0,0,0},{0,0,0,0},{0,0,0,0}};
    float xn[4][4];
    const int tg0 = ch * 16;

    {
        const size_t b0 = ((size_t)(jt * 128 + tg0) * 512) * 64 + f;
        #pragma unroll
        for (int T = 0; T < 4; ++T) {
            f16x4 zv;
            #pragma unroll
            for (int r4 = 0; r4 < 4; ++r4)
                zv[r4] = (_Float16)xs[b0 + (size_t)(rowbase + T * 16 + q * 4 + r4) * 64];
            *(f16x4*)&Z[0][nI * ZROW + rowbase + T * 16 + q * 4] = zv;
        }
        const size_t b1 = ((size_t)(jt * 128 + tg0 + 1) * 512) * 64 + f;
        #pragma unroll
        for (int T = 0; T < 4; ++T)
            #pragma unroll
            for (int r4 = 0; r4 < 4; ++r4)
                xn[T][r4] = xs[b1 + (size_t)(rowbase + T * 16 + q * 4 + r4) * 64];
    }
    __syncthreads();

    for (int t = 0; t < 16; ++t) {
        const _Float16* zb = &Z[t & 1][nI * ZROW];
        f32x4 acc0 = {0,0,0,0}, acc1 = {0,0,0,0}, acc2 = {0,0,0,0}, acc3 = {0,0,0,0};
        #pragma unroll
        for (int kk = 0; kk < 16; ++kk) {
            f16x8 b  = *(const f16x8*)&zb[kk * 32 + q * 8];
            f16x8 v2 = *(const f16x8*)&m2[kk * 32 + q * 8];
            f16x8 v3 = *(const f16x8*)&m3[kk * 32 + q * 8];
            acc0 = MF(a0[kk], b, acc0);
            acc1 = MF(a1[kk], b, acc1);
            acc2 = MF(v2,     b, acc2);
            acc3 = MF(v3,     b, acc3);
        }
        #pragma unroll
        for (int r4 = 0; r4 < 4; ++r4) {
            Y[0][r4] += acc0[r4] * (1.f / 256.f);
            Y[1][r4] += acc1[r4] * (1.f / 256.f);
            Y[2][r4] += acc2[r4] * (1.f / 256.f);
            Y[3][r4] += acc3[r4] * (1.f / 256.f);
        }
        if (t < 15) {
            _Float16* zn = &Z[(t + 1) & 1][nI * ZROW];
            #pragma unroll
            for (int T = 0; T < 4; ++T) {
                f16x4 zv;
                #pragma unroll
                for (int r4 = 0; r4 < 4; ++r4)
                    zv[r4] = (_Float16)(xn[T][r4] - Y[T][r4]);
                *(f16x4*)&zn[rowbase + T * 16 + q * 4] = zv;
            }
            if (t < 14) {
                const size_t bn = ((size_t)(jt * 128 + tg0 + t + 2) * 512) * 64 + f;
                #pragma unroll
                for (int T = 0; T < 4; ++T)
                    #pragma unroll
                    for (int r4 = 0; r4 < 4; ++r4)
                        xn[T][r4] = xs[bn + (size_t)(rowbase + T * 16 + q * 4 + r4) * 64];
            }
            __syncthreads();
        }
    }

    _Float16* st = state + ((size_t)(ch * 8 + jt) * 64 + f) * 512;
    #pragma unroll
    for (int T = 0; T < 4; ++T) {
        f16x4 sv;
        #pragma unroll
        for (int r4 = 0; r4 < 4; ++r4) sv[r4] = (_Float16)Y[T][r4];
        *(unsigned long long*)&st[rowbase + T * 16 + q * 4] = pack4(sv);
    }
}

// ---------------------------------------------------------------------------
// K7: carry update for chunk cch: state[cch] += G16 @ state[cch-1]  (in place).
// 32 blocks x 512 threads: bx = jt*4 + cg.
// ---------------------------------------------------------------------------
__launch_bounds__(512)
__global__ void k_carry(unsigned char* __restrict__ wsb, int cch)
{
    const _Float16* G16h = (const _Float16*)(wsb + OFF_G0);           // rm hi (256*G16)
    const _Float16* G16l = (const _Float16*)(wsb + OFF_G0) + GSUB;    // rm lo
    _Float16* state = (_Float16*)(wsb + OFF_STATE);

    const int tid = threadIdx.x;
    const int lane = tid & 63, wv = tid >> 6, q = lane >> 4, nI = lane & 15;
    const int bx = blockIdx.x;
    const int jt = bx >> 2, cg = bx & 3;
    const int rowbase = wv * 64;
    const int f = cg * 16 + nI;

    const _Float16* yprev = state + ((size_t)((cch - 1) * 8 + jt) * 64 + f) * 512;
    _Float16*       ycur  = state + ((size_t)(cch * 8 + jt) * 64 + f) * 512;

    f32x4 acc[4] = {{0,0,0,0},{0,0,0,0},{0,0,0,0},{0,0,0,0}};
    #pragma unroll 4
    for (int kk = 0; kk < 16; ++kk) {
        f16x8 b = *(const f16x8*)&yprev[kk * 32 + q * 8];
        #pragma unroll
        for (int T = 0; T < 4; ++T) {
            f16x8 ah = *(const f16x8*)&G16h[(size_t)(rowbase + T * 16 + nI) * 512 + kk * 32 + q * 8];
            f16x8 al = *(const f16x8*)&G16l[(size_t)(rowbase + T * 16 + nI) * 512 + kk * 32 + q * 8];
            acc[T] = MF(ah, b, acc[T]);
            acc[T] = MF(al, b, acc[T]);
        }
    }
    #pragma unroll
    for (int T = 0; T < 4; ++T) {
        f16x4 e4 = *(f16x4*)&ycur[rowbase + T * 16 + q * 4];
        f16x4 nv;
        #pragma unroll
        for (int r4 = 0; r4 < 4; ++r4)
            nv[r4] = (_Float16)((float)e4[r4] + acc[T][r4] * (1.f / 256.f));
        *(unsigned long long*)&ycur[rowbase + T * 16 + q * 4] = pack4(nv);
    }
}

// ---------------------------------------------------------------------------
// K8: phase-2 final chunk scan with carry-in; writes out (nontemporal).
// Same XCD-sibling swizzle as K6; launch_bounds(512,1) for 256-VGPR budget.
// ---------------------------------------------------------------------------
__launch_bounds__(512, 1)
__global__ void k_phase2(const float* __restrict__ xs, unsigned char* __restrict__ wsb,
                         float* __restrict__ out)
{
    const _Float16* Mrm = (const _Float16*)(wsb + OFF_XRM1);
    const _Float16* state = (const _Float16*)(wsb + OFF_STATE);

    const int tid = threadIdx.x;
    const int lane = tid & 63, wv = tid >> 6, q = lane >> 4, nI = lane & 15;
    const int bx = blockIdx.x;
    const int cg = bx >> 6, ch = (bx >> 3) & 7, jt = bx & 7;   // XCD-sibling swizzle
    const int rowbase = wv * 64;
    const int f = cg * 16 + nI;

    __shared__ _Float16 Z[2][16 * ZROW];

    f16x8 a0[16], a1[16];
    #pragma unroll
    for (int kk = 0; kk < 16; ++kk)
        a0[kk] = *(const f16x8*)&Mrm[(size_t)(rowbase + nI) * 512 + kk * 32 + q * 8];
    #pragma unroll
    for (int kk = 0; kk < 16; ++kk)
        a1[kk] = *(const f16x8*)&Mrm[(size_t)(rowbase + 16 + nI) * 512 + kk * 32 + q * 8];
    const _Float16* m2 = &Mrm[(size_t)(rowbase + 32 + nI) * 512];
    const _Float16* m3 = &Mrm[(size_t)(rowbase + 48 + nI) * 512];

    f32x4 Y[4];
    if (ch == 0) {
        #pragma unroll
        for (int T = 0; T < 4; ++T)
            #pragma unroll
            for (int r4 = 0; r4 < 4; ++r4) Y[T][r4] = 0.f;
    } else {
        const _Float16* st = state + ((size_t)((ch - 1) * 8 + jt) * 64 + f) * 512;
        #pragma unroll
        for (int T = 0; T < 4; ++T) {
            f16x4 sv = *(const f16x4*)&st[rowbase + T * 16 + q * 4];
            #pragma unroll
            for (int r4 = 0; r4 < 4; ++r4) Y[T][r4] = (float)sv[r4];
        }
    }

    float xn[4][4];
    const int tg0 = ch * 16;
    {
        const size_t b0 = ((size_t)(jt * 128 + tg0) * 512) * 64 + f;
        #pragma unroll
        for (int T = 0; T < 4; ++T) {
            f16x4 zv;
            #pragma unroll
            for (int r4 = 0; r4 < 4; ++r4) {
                float xv = xs[b0 + (size_t)(rowbase + T * 16 + q * 4 + r4) * 64];
                zv[r4] = (_Float16)(xv - Y[T][r4]);
            }
            *(f16x4*)&Z[0][nI * ZROW + rowbase + T * 16 + q * 4] = zv;
        }
        const size_t b1 = ((size_t)(jt * 128 + tg0 + 1) * 512) * 64 + f;
        #pragma unroll
        for (int T = 0; T < 4; ++T)
            #pragma unroll
            for (int r4 = 0; r4 < 4; ++r4)
                xn[T][r4] = xs[b1 + (size_t)(rowbase + T * 16 + q * 4 + r4) * 64];
    }
    __syncthreads();

    for (int t = 0; t < 16; ++t) {
        const _Float16* zb = &Z[t & 1][nI * ZROW];
        f32x4 acc0 = {0,0,0,0}, acc1 = {0,0,0,0}, acc2 = {0,0,0,0}, acc3 = {0,0,0,0};
        #pragma unroll
        for (int kk = 0; kk < 16; ++kk) {
            f16x8 b  = *(const f16x8*)&zb[kk * 32 + q * 8];
            f16x8 v2 = *(const f16x8*)&m2[kk * 32 + q * 8];
            f16x8 v3 = *(const f16x8*)&m3[kk * 32 + q * 8];
            acc0 = MF(a0[kk], b, acc0);
            acc1 = MF(a1[kk], b, acc1);
            acc2 = MF(v2,     b, acc2);
            acc3 = MF(v3,     b, acc3);
        }
        const size_t base = ((size_t)(jt * 128 + tg0 + t) * 512) * 64 + f;
        #pragma unroll
        for (int r4 = 0; r4 < 4; ++r4) {
            Y[0][r4] += acc0[r4] * (1.f / 256.f);
            Y[1][r4] += acc1[r4] * (1.f / 256.f);
            Y[2][r4] += acc2[r4] * (1.f / 256.f);
            Y[3][r4] += acc3[r4] * (1.f / 256.f);
        }
        #pragma unroll
        for (int T = 0; T < 4; ++T)
            #pragma unroll
            for (int r4 = 0; r4 < 4; ++r4)
                __builtin_nontemporal_store(Y[T][r4],
                    &out[base + (size_t)(rowbase + T * 16 + q * 4 + r4) * 64]);

        if (t < 15) {
            _Float16* zn = &Z[(t + 1) & 1][nI * ZROW];
            #pragma unroll
            for (int T = 0; T < 4; ++T) {
                f16x4 zv;
                #pragma unroll
                for (int r4 = 0; r4 < 4; ++r4)
                    zv[r4] = (_Float16)(xn[T][r4] - Y[T][r4]);
                *(f16x4*)&zn[rowbase + T * 16 + q * 4] = zv;
            }
            if (t < 14) {
                const size_t bn = ((size_t)(jt * 128 + tg0 + t + 2) * 512) * 64 + f;
                #pragma unroll
                for (int T = 0; T < 4; ++T)
                    #pragma unroll
                    for (int r4 = 0; r4 < 4; ++r4)
                        xn[T][r4] = xs[bn + (size_t)(rowbase + T * 16 + q * 4 + r4) * 64];
            }
            __syncthreads();
        }
    }
}

extern "C" void kernel_launch(void* const* d_in, const int* in_sizes, int n_in,
                              void* d_out, int out_size, void* d_ws, size_t ws_size,
                              hipStream_t stream)
{
    const float* xs = (const float*)d_in[0];   // [8,128,512,64] fp32
    const float* A  = (const float*)d_in[1];   // [1,512,512] fp32
    float* out = (float*)d_out;                // [8,128,512,64] fp32
    unsigned char* ws = (unsigned char*)d_ws;  // ~12.6 MB used

    k_prep_rows<<<dim3(32), dim3(256), 0, stream>>>(A, ws);
    k_init_x<<<dim3(32), dim3(256), 0, stream>>>(ws);

    for (int nit = 0; nit < NITER; ++nit) {
        k_newton_e<<<dim3(256), dim3(256), 0, stream>>>(ws, nit);
        k_newton_u<<<dim3(256), dim3(256), 0, stream>>>(ws, nit);
    }

    k_gprep<<<dim3(32), dim3(256), 0, stream>>>(ws);
    _Float16* G0 = (_Float16*)(ws + OFF_G0);
    _Float16* G1 = (_Float16*)(ws + OFF_G1);
    k_gsq<<<dim3(256), dim3(256), 0, stream>>>(G0, G1);   // G^2
    k_gsq<<<dim3(256), dim3(256), 0, stream>>>(G1, G0);   // G^4
    k_gsq<<<dim3(256), dim3(256), 0, stream>>>(G0, G1);   // G^8
    k_gsq<<<dim3(256), dim3(256), 0, stream>>>(G1, G0);   // G^16 -> buf0

    k_phase1<<<dim3(256), dim3(512), 0, stream>>>(xs, ws);
    for (int c = 1; c < 8; ++c)
        k_carry<<<dim3(32), dim3(512), 0, stream>>>(ws, c);
    k_phase2<<<dim3(256), dim3(512), 0, stream>>>(xs, ws, out);
}